// Round 8
// baseline (1452.704 us; speedup 1.0000x reference)
//
#include <hip/hip_runtime.h>
#include <math.h>

#define HH 376
#define WW 376
#define HWSZ (HH*WW)          // 141376
#define NSC (3*HWSZ)          // 424128
#define KTOP 500
#define CAND_CAP 65536
#define SORT_M 4096
#define NBIN 65536

// convb4 tiling: 32x4 px tile, 256 threads (4 waves), wave = 8 ocs,
// block handles 32 ocs (blockIdx.z parity). Grid 12x94x2 = 2256 blocks.
#define CICB 4
#define CSINW 34
#define CSINH 6
#define CNLOAD (CICB*CSINH*CSINW)   // 816

// head tiling: 32x8 px tile, 256 threads, ICB 4. Grid 12x47 = 564 blocks.
#define H2_ICB 4
#define H2_SINH 10
#define H2_SINW 34
#define H2_NLOAD (H2_ICB*H2_SINH*H2_SINW)  // 1360

__device__ __constant__ int d_pb[6] = {0, 3, 5, 6, 9, 11};
__device__ __constant__ int d_nc[6] = {3, 2, 1, 3, 2, 1};
__device__ __constant__ int d_goff[6] = {0, 0, 2, 3, 6, 8};  // g-slot base per branch

// ---------------------------------------------------------------------------
// Weight reorder -> ic-major [b][IC][64][12] (9 real + 3 pad); offset for
// (ic,oc) = ic*768 + oc*12. Wave-uniform in convb (scalar loads); 16B-aligned
// rows for branchpx float4 loads.
// ---------------------------------------------------------------------------
__global__ void reorder_w12_kernel(const float* __restrict__ src, float* __restrict__ dst,
                                   int IC, int total)
{
    int i = blockIdx.x*256 + threadIdx.x;
    if (i >= total) return;
    int per = IC*64*12;
    int b  = i / per;
    int r  = i - b*per;
    int ic = r / 768;
    int r3 = r - ic*768;
    int oc = r3 / 12;
    int k  = r3 - oc*12;
    float v = 0.f;
    if (k < 9)
        v = src[(size_t)b*64*IC*9 + ((size_t)oc*IC + ic)*9 + k];
    dst[i] = v;
}

// head weight reorder: ic-major [b][64][3][9]; offset ic*27 + o*9.
__global__ void reorder_wh_kernel(const float* __restrict__ src, float* __restrict__ dst,
                                  int total)
{
    int i = blockIdx.x*256 + threadIdx.x;
    if (i >= total) return;
    int per = 3*64*9;
    int b = i / per;
    int j = i - b*per;
    int ic = j / 27;
    int rr = j - ic*27;
    int oc = rr / 9;
    int kk = rr - oc*9;
    dst[i] = src[b*per + (oc*64 + ic)*9 + kk];
}

// ---------------------------------------------------------------------------
// convb4: 3x3 SAME conv, IC -> 64 oc (32 per block), BN+ReLU. 32x4 tile,
// 256 threads; thread = 8 ocs x 2 px (acc 16). Wave-uniform oc group ->
// scalar weight loads. Grid 2256 blocks = 8.8 blocks/CU (vs 4.4 before):
// saturates the 8-block/CU thread limit so latency hides under other waves.
// Accumulation order (ic asc, w0..w8 chain) bit-identical to rounds 2-7 --
// REQUIRED on the hm path (top-k ordering).
// ---------------------------------------------------------------------------
template<int IC>
__global__ __launch_bounds__(256) void convb_kernel(
    const float* __restrict__ in,    // [IC][H][W]
    const float* __restrict__ rw,    // [br][IC][64][12]
    const float* __restrict__ bn,    // [br][4][64]
    float* __restrict__ out)         // [br][64][H][W]
{
    __shared__ float s_in[CICB][CSINH][CSINW];

    const int tid  = threadIdx.x;
    const int x0   = blockIdx.x * 32;
    const int y0   = blockIdx.y * 4;
    const int br   = blockIdx.z >> 1;
    const int half = blockIdx.z & 1;
    const int col  = tid & 31;
    const int rh   = (tid >> 5) & 1;   // rows rh*2, rh*2+1
    const int uslot = __builtin_amdgcn_readfirstlane(tid >> 6);  // 0..3

    const float* rwb = rw + (size_t)br * IC * 768;
    const float* bnb = bn + br * 256;
    float* outb = out + (size_t)br * 64 * HWSZ;

    float acc[8][2];
#pragma unroll
    for (int o = 0; o < 8; o++) { acc[o][0] = 0.f; acc[o][1] = 0.f; }

    float pf[4];
    int icbase = 0;
    auto do_prefetch = [&]() {
#pragma unroll
        for (int k = 0; k < 4; k++) {
            int idx = tid + k*256;
            int ic  = idx / 204;           // 6*34 per ic
            int rem = idx - ic*204;
            int r   = rem / 34;
            int c   = rem - r*34;
            int gy  = y0 + r - 1;
            int gx  = x0 + c - 1;
            bool v  = (idx < CNLOAD) && (gy >= 0) && (gy < HH) && (gx >= 0) && (gx < WW);
            pf[k] = v ? in[(size_t)(icbase+ic)*HWSZ + gy*WW + gx] : 0.f;
        }
    };
    do_prefetch();

    float* flat = &s_in[0][0][0];

    for (int ic0 = 0; ic0 < IC; ic0 += CICB) {
        __syncthreads();
#pragma unroll
        for (int k = 0; k < 3; k++) flat[tid + k*256] = pf[k];
        if (tid < CNLOAD - 3*256) flat[tid + 3*256] = pf[3];
        __syncthreads();
        if (ic0 + CICB < IC) { icbase = ic0 + CICB; do_prefetch(); }

#pragma unroll 1
        for (int ic = 0; ic < CICB; ic++) {
            float vin[4][3];
#pragma unroll
            for (int r = 0; r < 4; r++) {
                vin[r][0] = s_in[ic][rh*2 + r][col];
                vin[r][1] = s_in[ic][rh*2 + r][col+1];
                vin[r][2] = s_in[ic][rh*2 + r][col+2];
            }
            const float* wic = rwb + (size_t)(ic0 + ic)*768 + half*384 + uslot*96;
#pragma unroll
            for (int o = 0; o < 8; o++) {
                const float* wp = wic + o*12;
                float w0=wp[0],w1=wp[1],w2=wp[2],w3=wp[3],w4=wp[4],
                      w5=wp[5],w6=wp[6],w7=wp[7],w8=wp[8];
#pragma unroll
                for (int j = 0; j < 2; j++) {
                    float s = acc[o][j];
                    s = fmaf(w0, vin[j  ][0], s);
                    s = fmaf(w1, vin[j  ][1], s);
                    s = fmaf(w2, vin[j  ][2], s);
                    s = fmaf(w3, vin[j+1][0], s);
                    s = fmaf(w4, vin[j+1][1], s);
                    s = fmaf(w5, vin[j+1][2], s);
                    s = fmaf(w6, vin[j+2][0], s);
                    s = fmaf(w7, vin[j+2][1], s);
                    s = fmaf(w8, vin[j+2][2], s);
                    acc[o][j] = s;
                }
            }
        }
    }

    const int gx = x0 + col;
    if (gx < WW) {
#pragma unroll
        for (int o = 0; o < 8; o++) {
            int oc = half*32 + uslot*8 + o;
            float g = bnb[oc], b = bnb[64+oc], m = bnb[128+oc], v = bnb[192+oc];
            float sc = g * rsqrtf(v + 1e-5f);
            float sh = b - m * sc;
#pragma unroll
            for (int j = 0; j < 2; j++) {
                int gy = y0 + rh*2 + j;    // 94*4 = 376 exact
                float valo = fmaxf(fmaf(acc[o][j], sc, sh), 0.f);
                outb[(size_t)oc*HWSZ + (size_t)gy*WW + gx] = valo;
            }
        }
    }
}

// ---------------------------------------------------------------------------
// head3 (hm only): 3x3 conv 64 -> 3 + bias; histograms sigmoid bits.
// Retiled 32x8 (564 blocks). Thread = 1 col x 1 row x 3 ocs. Bit-exact.
// ---------------------------------------------------------------------------
__global__ __launch_bounds__(256) void head3_kernel(
    const float* __restrict__ in,        // [64][H][W]  (hm h1)
    const float* __restrict__ rwh_all,   // [6][64][3][9]
    const float* __restrict__ bias_all,  // [6][3]
    float* __restrict__ outs,            // 3 hm planes
    unsigned* __restrict__ hist)
{
    __shared__ float s_in[H2_ICB][H2_SINH][H2_SINW];

    const float* rwh = rwh_all;          // branch 0
    const float* bias = bias_all;

    const int tid = threadIdx.x;
    const int x0  = blockIdx.x * 32;
    const int y0  = blockIdx.y * 8;
    const int col = tid & 31;
    const int rs  = tid >> 5;            // row 0..7

    float acc[3];
#pragma unroll
    for (int o = 0; o < 3; o++) acc[o] = 0.f;

    float pf[6];
    int icbase = 0;
    auto do_prefetch = [&]() {
#pragma unroll
        for (int k = 0; k < 6; k++) {
            int idx = tid + k*256;
            int ic  = idx / 340;           // 10*34 per ic
            int rem = idx - ic*340;
            int r   = rem / 34;
            int c   = rem - r*34;
            int gy  = y0 + r - 1;
            int gx  = x0 + c - 1;
            bool v  = (idx < H2_NLOAD) && (gy >= 0) && (gy < HH) && (gx >= 0) && (gx < WW);
            pf[k] = v ? in[(size_t)(icbase+ic)*HWSZ + gy*WW + gx] : 0.f;
        }
    };
    do_prefetch();

    float* flat = &s_in[0][0][0];

    for (int ic0 = 0; ic0 < 64; ic0 += H2_ICB) {
        __syncthreads();
#pragma unroll
        for (int k = 0; k < 5; k++) flat[tid + k*256] = pf[k];
        if (tid < H2_NLOAD - 5*256) flat[tid + 5*256] = pf[5];
        __syncthreads();
        if (ic0 + H2_ICB < 64) { icbase = ic0 + H2_ICB; do_prefetch(); }

#pragma unroll 1
        for (int ic = 0; ic < H2_ICB; ic++) {
            float vin[3][3];
#pragma unroll
            for (int r = 0; r < 3; r++) {
                vin[r][0] = s_in[ic][rs + r][col];
                vin[r][1] = s_in[ic][rs + r][col+1];
                vin[r][2] = s_in[ic][rs + r][col+2];
            }
            const float* wic = rwh + (ic0 + ic)*27;
#pragma unroll
            for (int o = 0; o < 3; o++) {
                const float* wp = wic + o*9;
                float s = acc[o];
                s = fmaf(wp[0], vin[0][0], s);
                s = fmaf(wp[1], vin[0][1], s);
                s = fmaf(wp[2], vin[0][2], s);
                s = fmaf(wp[3], vin[1][0], s);
                s = fmaf(wp[4], vin[1][1], s);
                s = fmaf(wp[5], vin[1][2], s);
                s = fmaf(wp[6], vin[2][0], s);
                s = fmaf(wp[7], vin[2][1], s);
                s = fmaf(wp[8], vin[2][2], s);
                acc[o] = s;
            }
        }
    }

    const int gx = x0 + col;
    const int gy = y0 + rs;              // 47*8 = 376 exact
    if (gx < WW) {
#pragma unroll
        for (int o = 0; o < 3; o++) {
            float v = acc[o] + bias[o];
            outs[(size_t)o*HWSZ + (size_t)gy*WW + gx] = v;
            float sc = 1.f / (1.f + expf(-v));
            atomicAdd(&hist[__float_as_uint(sc) >> 16], 1u);
        }
    }
}

// ---------------------------------------------------------------------------
// Top-K: hist (in head3) -> scan -> collect -> sort (writes sorted[500]).
// ---------------------------------------------------------------------------
__global__ void scan_kernel(const unsigned* __restrict__ hist, unsigned* __restrict__ meta)
{
    __shared__ unsigned part[1024];
    __shared__ unsigned scn[1024];
    __shared__ int tcs;
    const int t = threadIdx.x;
    unsigned ssum = 0;
    for (int b = t*64; b < t*64 + 64; b++) ssum += hist[b];
    part[t] = ssum;
    scn[t] = ssum;
    __syncthreads();
    for (int off = 1; off < 1024; off <<= 1) {
        unsigned v = (t + off < 1024) ? scn[t + off] : 0u;
        __syncthreads();
        scn[t] += v;
        __syncthreads();
    }
    unsigned sufEx = scn[t] - part[t];
    if (sufEx < KTOP && scn[t] >= KTOP) tcs = t;
    __syncthreads();
    if (t == 0) {
        int tc = tcs;
        unsigned c = scn[tc] - part[tc];
        unsigned B = tc * 64;
        for (int b = tc*64 + 63; b >= tc*64; b--) {
            c += hist[b];
            if (c >= KTOP) { B = (unsigned)b; break; }
        }
        meta[0] = B;
        meta[1] = 0;
    }
}

__global__ void collect_kernel(const float* __restrict__ hm,
                               unsigned* __restrict__ meta,
                               unsigned long long* __restrict__ cand)
{
    int i = blockIdx.x * 256 + threadIdx.x;
    if (i >= NSC) return;
    float sc = 1.f / (1.f + expf(-hm[i]));
    unsigned key = __float_as_uint(sc);
    if ((key >> 16) >= meta[0]) {
        unsigned pos = atomicAdd(&meta[1], 1u);
        if (pos < CAND_CAP)
            cand[pos] = ((unsigned long long)key << 32) | (unsigned)(0xFFFFFFFFu - (unsigned)i);
    }
}

__global__ void topk_sort_kernel(const unsigned* __restrict__ meta,
                                 const unsigned long long* __restrict__ cand,
                                 unsigned long long* __restrict__ sorted)
{
    extern __shared__ unsigned long long s[];
    __shared__ unsigned long long red[512];
    const int t = threadIdx.x;
    unsigned n = meta[1];
    if (n > CAND_CAP) n = CAND_CAP;

    if (n <= SORT_M) {
        unsigned m = 1024;
        while (m < n) m <<= 1;
        for (unsigned i = t; i < m; i += 512) s[i] = (i < n) ? cand[i] : 0ULL;
        __syncthreads();
        for (unsigned k = 2; k <= m; k <<= 1) {
            for (unsigned j = k >> 1; j > 0; j >>= 1) {
                for (unsigned i = t; i < m; i += 512) {
                    unsigned ixj = i ^ j;
                    if (ixj > i) {
                        unsigned long long a = s[i], b = s[ixj];
                        bool desc = ((i & k) == 0);
                        if (desc ? (a < b) : (a > b)) { s[i] = b; s[ixj] = a; }
                    }
                }
                __syncthreads();
            }
        }
    } else {
        unsigned long long last = 0xFFFFFFFFFFFFFFFFULL;
        for (int slot = 0; slot < KTOP; slot++) {
            unsigned long long best = 0;
            for (unsigned i = t; i < n; i += 512) {
                unsigned long long v = cand[i];
                if (v < last && v > best) best = v;
            }
            red[t] = best;
            __syncthreads();
            for (int off = 256; off > 0; off >>= 1) {
                if (t < off) { if (red[t+off] > red[t]) red[t] = red[t+off]; }
                __syncthreads();
            }
            if (t == 0) s[slot] = red[0];
            last = red[0];
            __syncthreads();
        }
    }
    __syncthreads();
    if (t < KTOP) sorted[t] = s[t];
}

// ---------------------------------------------------------------------------
// branchpx: evaluate branches 1..5 ONLY at the 500 selected pixels.
// Block = (slot, branch-1). Phase 1: h1 (64 oc) on the 3x3 neighborhood from
// the full-plane shared (5x5 window, zero-padded). Phase 2: head dot + bias.
// fp32 accumulation, order-free (only hm needs bit-exactness).
// ---------------------------------------------------------------------------
__global__ __launch_bounds__(256) void branchpx_kernel(
    const unsigned long long* __restrict__ sorted,   // [500]
    const float* __restrict__ fsh,                   // shared [64][H][W]
    const float* __restrict__ rwbr,                  // [6][64ic][64oc][12]
    const float* __restrict__ rwhd,                  // [6][64ic][3][9]
    const float* __restrict__ bn1s,                  // [6][4][64]
    const float* __restrict__ b2s,                   // [6][3]
    float* __restrict__ g)                           // [500][9]
{
    __shared__ float sh[64*28];          // [ic][25 pad 28]
    __shared__ float part[4*9*64];       // [icq][p][oc]
    __shared__ float h1s[9*64];          // [p][oc]
    __shared__ float red[3*64];          // [o][ic]

    const int slot = blockIdx.x;
    const int br   = 1 + blockIdx.y;     // 1..5
    const int tid  = threadIdx.x;

    unsigned long long e = sorted[slot];
    unsigned idx = 0xFFFFFFFFu - (unsigned)(e & 0xFFFFFFFFu);
    int sp = (int)(idx % HWSZ);
    int py = sp / WW, px = sp % WW;

    // ---- stage shared 5x5 x 64ic, zero-padded ----
    for (int ee = tid; ee < 1600; ee += 256) {
        int ic = ee / 25;
        int p  = ee - ic*25;
        int dy = p / 5, dx = p - dy*5;
        int gy = py + dy - 2, gx = px + dx - 2;
        float v = 0.f;
        if (gy >= 0 && gy < HH && gx >= 0 && gx < WW)
            v = fsh[(size_t)ic*HWSZ + gy*WW + gx];
        sh[ic*28 + p] = v;
    }
    __syncthreads();

    // ---- phase 1: partial h1 over ic quarter ----
    const int oc  = tid & 63;
    const int icq = tid >> 6;            // 0..3
    const float* rwblk = rwbr + (size_t)br*49152;   // [ic][oc][12]

    float acc[9];
#pragma unroll
    for (int p = 0; p < 9; p++) acc[p] = 0.f;

#pragma unroll 1
    for (int icl = 0; icl < 16; icl++) {
        int ic = icq*16 + icl;
        const float* wp = rwblk + (size_t)ic*768 + oc*12;
        float4 wA = *(const float4*)(wp);
        float4 wB = *(const float4*)(wp + 4);
        float w8 = wp[8];
        const float* srow = &sh[ic*28];
        float s_[25];
#pragma unroll
        for (int q = 0; q < 6; q++) {
            float4 v = *(const float4*)(srow + q*4);
            s_[q*4+0] = v.x; s_[q*4+1] = v.y; s_[q*4+2] = v.z; s_[q*4+3] = v.w;
        }
        s_[24] = srow[24];
#pragma unroll
        for (int ty = 0; ty < 3; ty++) {
#pragma unroll
            for (int tx = 0; tx < 3; tx++) {
                int p = ty*3 + tx;
                float s = acc[p];
                s = fmaf(wA.x, s_[(ty  )*5 + tx  ], s);
                s = fmaf(wA.y, s_[(ty  )*5 + tx+1], s);
                s = fmaf(wA.z, s_[(ty  )*5 + tx+2], s);
                s = fmaf(wA.w, s_[(ty+1)*5 + tx  ], s);
                s = fmaf(wB.x, s_[(ty+1)*5 + tx+1], s);
                s = fmaf(wB.y, s_[(ty+1)*5 + tx+2], s);
                s = fmaf(wB.z, s_[(ty+2)*5 + tx  ], s);
                s = fmaf(wB.w, s_[(ty+2)*5 + tx+1], s);
                s = fmaf(w8,   s_[(ty+2)*5 + tx+2], s);
                acc[p] = s;
            }
        }
    }
#pragma unroll
    for (int p = 0; p < 9; p++) part[(icq*9 + p)*64 + oc] = acc[p];
    __syncthreads();

    // ---- reduce + BN + ReLU + head-conv zero-pad ----
    const float* bnb = bn1s + br*256;
    for (int v = tid; v < 576; v += 256) {
        int p = v >> 6, o = v & 63;
        float x = part[(0*9+p)*64+o] + part[(1*9+p)*64+o]
                + part[(2*9+p)*64+o] + part[(3*9+p)*64+o];
        float gg = bnb[o], bb = bnb[64+o], mm = bnb[128+o], vv = bnb[192+o];
        float sc = gg * rsqrtf(vv + 1e-5f);
        float shf = bb - mm * sc;
        float h1v = fmaxf(fmaf(x, sc, shf), 0.f);
        int ty = p / 3 - 1, tx = p % 3 - 1;
        int gy = py + ty, gx = px + tx;
        if (gy < 0 || gy >= HH || gx < 0 || gx >= WW) h1v = 0.f;
        h1s[p*64 + o] = h1v;
    }
    __syncthreads();

    // ---- phase 2: head partials ----
    if (tid < 192) {
        int o = tid >> 6, ic = tid & 63;
        const float* wh = rwhd + (size_t)br*1728 + ic*27 + o*9;
        float s = 0.f;
#pragma unroll
        for (int k = 0; k < 9; k++) s = fmaf(wh[k], h1s[k*64 + ic], s);
        red[o*64 + ic] = s;
    }
    __syncthreads();

    if (tid < 3 && tid < d_nc[br]) {
        float s = b2s[br*3 + tid];
        for (int ic = 0; ic < 64; ic++) s += red[tid*64 + ic];
        g[slot*9 + d_goff[br] + tid] = s;
    }
}

// ---------------------------------------------------------------------------
// finish: assemble boxes/scores/cls from sorted keys + gathered g values.
// ---------------------------------------------------------------------------
__global__ void finish_kernel(const unsigned long long* __restrict__ sorted,
                              const float* __restrict__ g,
                              float* __restrict__ dout)
{
    int t = blockIdx.x*256 + threadIdx.x;
    if (t >= KTOP) return;
    unsigned long long e = sorted[t];
    unsigned key = (unsigned)(e >> 32);
    unsigned idx = 0xFFFFFFFFu - (unsigned)(e & 0xFFFFFFFFu);
    int cls = (int)(idx / HWSZ);
    int sp  = (int)(idx % HWSZ);
    float ys = (float)(sp / WW);
    float xs = (float)(sp % WW);
    float shm = __uint_as_float(key);

    const float* gg = g + t*9;
    float ct0 = gg[0], ct1 = gg[1], cz = gg[2];
    float d0 = expf(gg[3]), d1 = expf(gg[4]), d2 = expf(gg[5]);
    float r0 = gg[6], r1 = gg[7], iou = gg[8];

    float xg = (xs + ct0) * 4.0f * 0.1f + (-75.2f);
    float yg = (ys + ct1) * 4.0f * 0.1f + (-75.2f);
    float heading = atan2f(r1, r0);
    iou = (iou + 1.f) * 0.5f;
    iou = fminf(fmaxf(iou, 0.f), 1.f);
    const float RECT[3] = {0.68f, 0.71f, 0.65f};
    float r = RECT[cls];
    float score = powf(shm, 1.f - r) * powf(iou, r);
    score = (score > 0.1f) ? score : 0.f;

    dout[t*7+0] = xg;  dout[t*7+1] = yg;  dout[t*7+2] = cz;
    dout[t*7+3] = d0;  dout[t*7+4] = d1;  dout[t*7+5] = d2;
    dout[t*7+6] = heading;
    dout[3500 + t] = score;
    dout[4000 + t] = (float)cls;
}

// ---------------------------------------------------------------------------
extern "C" void kernel_launch(void* const* d_in, const int* in_sizes, int n_in,
                              void* d_out, int out_size, void* d_ws, size_t ws_size,
                              hipStream_t stream)
{
    const float* x    = (const float*)d_in[0];   // [256][376][376]
    const float* W_sh = (const float*)d_in[1];   // [64][256][9]
    const float* bn_sh= (const float*)d_in[2];   // [4][64]
    const float* W1s  = (const float*)d_in[3];   // [6][64][64][9]
    const float* bn1s = (const float*)d_in[4];   // [6][4][64]
    const float* W2s  = (const float*)d_in[5];   // [6][3][64][9]
    const float* b2s  = (const float*)d_in[6];   // [6][3]
    float* dout = (float*)d_out;

    char* ws = (char*)d_ws;
    const size_t SHARED_B = (size_t)64*HWSZ*4;            // 36,192,256
    const size_t OFF_SHARED = 0;
    const size_t OFF_H1     = OFF_SHARED + SHARED_B;
    const size_t OFF_OUTS   = OFF_H1     + SHARED_B;      // 3 hm planes
    const size_t OFF_HIST   = OFF_OUTS   + (size_t)3*HWSZ*4;
    const size_t OFF_META   = OFF_HIST   + (size_t)NBIN*4;
    const size_t OFF_SORTED = OFF_META   + 256;
    const size_t OFF_G      = OFF_SORTED + (size_t)KTOP*8;
    const size_t OFF_CAND   = OFF_G      + (size_t)KTOP*9*4 + 64;
    const size_t OFF_RWSH   = OFF_CAND   + (size_t)CAND_CAP*8;
    const size_t OFF_RWBR   = OFF_RWSH   + (size_t)196608*4;
    const size_t OFF_RWHD   = OFF_RWBR   + (size_t)294912*4;

    float* f_shared = (float*)(ws + OFF_SHARED);
    float* f_h1     = (float*)(ws + OFF_H1);
    float* f_outs   = (float*)(ws + OFF_OUTS);
    unsigned* hist  = (unsigned*)(ws + OFF_HIST);
    unsigned* meta  = (unsigned*)(ws + OFF_META);
    unsigned long long* sorted = (unsigned long long*)(ws + OFF_SORTED);
    float* gbuf     = (float*)(ws + OFF_G);
    unsigned long long* cand = (unsigned long long*)(ws + OFF_CAND);
    float* rwsh = (float*)(ws + OFF_RWSH);
    float* rwbr = (float*)(ws + OFF_RWBR);
    float* rwhd = (float*)(ws + OFF_RWHD);

    dim3 blk(256);

    hipMemsetAsync(hist, 0, (size_t)NBIN*4, stream);

    // ---- weight reorders ----
    reorder_w12_kernel<<<(196608+255)/256, blk, 0, stream>>>(W_sh, rwsh, 256, 196608);
    reorder_w12_kernel<<<(294912+255)/256, blk, 0, stream>>>(W1s,  rwbr,  64, 294912);
    reorder_wh_kernel<<<(10368+255)/256,  blk, 0, stream>>>(W2s, rwhd, 10368);

    // ---- hm chain (bit-exact fp32) ----
    convb_kernel<256><<<dim3(12,94,2), blk, 0, stream>>>(x, rwsh, bn_sh, f_shared);
    convb_kernel<64><<<dim3(12,94,2), blk, 0, stream>>>(f_shared, rwbr, bn1s, f_h1);
    head3_kernel<<<dim3(12,47,1), blk, 0, stream>>>(f_h1, rwhd, b2s, f_outs, hist);

    // ---- top-k ----
    scan_kernel<<<1, 1024, 0, stream>>>(hist, meta);
    dim3 gscan((NSC + 255)/256);
    collect_kernel<<<gscan, blk, 0, stream>>>(f_outs, meta, cand);
    topk_sort_kernel<<<1, 512, SORT_M*sizeof(unsigned long long), stream>>>(
        meta, cand, sorted);

    // ---- branches 1..5 evaluated only at the 500 selected pixels ----
    branchpx_kernel<<<dim3(KTOP, 5), blk, 0, stream>>>(
        sorted, f_shared, rwbr, rwhd, bn1s, b2s, gbuf);

    // ---- assemble outputs ----
    finish_kernel<<<(KTOP+255)/256, blk, 0, stream>>>(sorted, gbuf, dout);

    (void)in_sizes; (void)n_in; (void)out_size; (void)ws_size;
}